// Round 2
// baseline (279.407 us; speedup 1.0000x reference)
//
#include <hip/hip_runtime.h>
#include <cstdint>

typedef unsigned short u16;
typedef unsigned int   u32;
typedef _Float16 f16;

typedef __attribute__((ext_vector_type(8))) _Float16 f16x8;   // 8 fp16 = 4 VGPRs
typedef __attribute__((ext_vector_type(4))) float    f32x4;   // MFMA accumulator

__device__ __forceinline__ u16 f2h(float f) {
    union { f16 h; u16 u; } c; c.h = (f16)f; return c.u;      // v_cvt_f16_f32 RTNE
}
__device__ __forceinline__ float h2f(u16 u) {
    union { u16 u; f16 h; } c; c.u = u; return (float)c.h;
}

// async global->LDS, 16B per lane; LDS dest = wave-uniform base + lane*16
__device__ __forceinline__ void async_copy16(const u16* g, u16* lds) {
    __builtin_amdgcn_global_load_lds(
        (const __attribute__((address_space(1))) void*)g,
        (__attribute__((address_space(3))) void*)lds,
        16, 0, 0);
}

// ---------------------------------------------------------------------------
// fp16 NT GEMM core, 2-phase double-buffered:
//   C[128,128] += A[128,K] * B[128,K]^T, K contiguous both.
// 256 thr = 4 waves (2x2), each wave 64x64 = 4x4 MFMA 16x16x32.  BK=32.
// LDS: 2 x (As[128][32] + Bs[128][32]) u16 = 32 KB.  XOR-swizzled.
// Pipeline: STAGE(t+1) issued BEFORE compute(t); one drain+barrier per tile
// (the compiler's implicit vmcnt(0)+lgkmcnt(0) before s_barrier is the drain).
// ---------------------------------------------------------------------------
__device__ __forceinline__ void gemm_nt_f16(
    u16* smem, const u16* __restrict__ A, int lda,
    const u16* __restrict__ B, int ldb, int K, f32x4 acc[4][4])
{
    const int t = threadIdx.x, w = t >> 6, lane = t & 63;
    const int srow = lane >> 2;                    // 0..15 within chunk
    const int skc  = (((lane & 3) ^ ((lane >> 3) & 3)) * 8);  // swizzled
    const int ra0 = (w*2+0)*16 + srow, ra1 = (w*2+1)*16 + srow;
    const u16* gA0 = A + (size_t)ra0 * lda + skc;
    const u16* gA1 = A + (size_t)ra1 * lda + skc;
    const u16* gB0 = B + (size_t)ra0 * ldb + skc;
    const u16* gB1 = B + (size_t)ra1 * ldb + skc;
    const int lo0 = (w*2+0)*512, lo1 = (w*2+1)*512;
    const int fr = lane & 15, fq = lane >> 4;
    const int fc = (fq ^ ((fr >> 1) & 3)) * 8;     // swizzled fragment chunk
    const int wm = (w >> 1) * 64, wn = (w & 1) * 64;
    const int fAo = (wm + fr) * 32 + fc;
    const int fBo = 4096 + (wn + fr) * 32 + fc;

#define STAGE_NT(buf, k0)                                          \
    {   u16* base = smem + (buf) * 8192;                           \
        async_copy16(gA0 + (k0), base + lo0);                      \
        async_copy16(gA1 + (k0), base + lo1);                      \
        async_copy16(gB0 + (k0), base + 4096 + lo0);               \
        async_copy16(gB1 + (k0), base + 4096 + lo1);  }

#define COMPUTE_NT(buf)                                            \
    {   const u16* bb = smem + (buf) * 8192;                       \
        f16x8 af[4], bf[4];                                        \
        _Pragma("unroll")                                          \
        for (int i = 0; i < 4; i++) af[i] = *(const f16x8*)(bb + fAo + i * 512); \
        _Pragma("unroll")                                          \
        for (int i = 0; i < 4; i++) bf[i] = *(const f16x8*)(bb + fBo + i * 512); \
        _Pragma("unroll")                                          \
        for (int mi = 0; mi < 4; mi++)                             \
            _Pragma("unroll")                                      \
            for (int ni = 0; ni < 4; ni++)                         \
                acc[mi][ni] = __builtin_amdgcn_mfma_f32_16x16x32_f16( \
                    af[mi], bf[ni], acc[mi][ni], 0, 0, 0);  }

    STAGE_NT(0, 0);
    __syncthreads();
    int cur = 0;
    for (int k0 = 32; k0 < K; k0 += 32) {
        STAGE_NT(cur ^ 1, k0);       // prefetch next tile (latency hides under MFMA)
        COMPUTE_NT(cur);
        __syncthreads();             // implicit vmcnt(0): next tile ready; cur reusable
        cur ^= 1;
    }
    COMPUTE_NT(cur);
#undef STAGE_NT
#undef COMPUTE_NT
}

__device__ __forceinline__ void zero_acc(f32x4 acc[4][4]) {
#pragma unroll
    for (int i = 0; i < 4; i++)
#pragma unroll
        for (int j = 0; j < 4; j++) {
            f32x4 z = {0.f, 0.f, 0.f, 0.f};
            acc[i][j] = z;
        }
}

// ---------------------------------------------------------------------------
// k_prep: blocks 0..511  : Wq -> duplicated f16 [512][1024] ([Wq|Wq]),
//                          Wk -> f16 [512][512]; zero rowsum accumulator s.
//         blocks 512..575: WvT[c][d] = f16(wv[d][c])
// ---------------------------------------------------------------------------
__global__ __launch_bounds__(256) void k_prep(const float* __restrict__ wq,
                                              const float* __restrict__ wk,
                                              const float* __restrict__ wv,
                                              u16* __restrict__ Wq2,
                                              u16* __restrict__ Wkh,
                                              u16* __restrict__ WvT,
                                              float* __restrict__ s)
{
    if (blockIdx.x < 512) {
        const int t = blockIdx.x * 256 + threadIdx.x;   // 0..131071
        if (t < 4096) s[t] = 0.f;
        const int e = t * 4;
        const int sel = e >> 18;                        // 0: wq, 1: wk
        const int off = e & 262143;
        const float* src = sel ? wk : wq;
        float4 v = *(const float4*)(src + off);
        ushort4 h;
        h.x = f2h(v.x); h.y = f2h(v.y); h.z = f2h(v.z); h.w = f2h(v.w);
        if (sel == 0) {
            int i = off >> 9, c = off & 511;
            *(ushort4*)(Wq2 + (size_t)i * 1024 + c) = h;
            *(ushort4*)(Wq2 + (size_t)i * 1024 + 512 + c) = h;
        } else {
            *(ushort4*)(Wkh + off) = h;
        }
    } else {
        __shared__ u16 tile[64][70];
        const int bx = blockIdx.x - 512;                // 0..63
        const int t = threadIdx.x;
        const int d0 = (bx >> 3) * 64;
        const int c0 = (bx & 7) * 64;
        const int rr = t >> 4, col4 = (t & 15) * 4;
#pragma unroll
        for (int i = 0; i < 4; i++) {
            int row = i * 16 + rr;                      // d offset
            float4 v = *(const float4*)(wv + (size_t)(d0 + row) * 512 + c0 + col4);
            ushort4 h;
            h.x = f2h(v.x); h.y = f2h(v.y); h.z = f2h(v.z); h.w = f2h(v.w);
            *(ushort4*)&tile[row][col4] = h;
        }
        __syncthreads();
#pragma unroll
        for (int i = 0; i < 4; i++) {
            int crow = i * 16 + rr;                     // c offset
            ushort4 o;
            o.x = tile[col4 + 0][crow];
            o.y = tile[col4 + 1][crow];
            o.z = tile[col4 + 2][crow];
            o.w = tile[col4 + 3][crow];
            *(ushort4*)(WvT + (size_t)(c0 + crow) * 512 + d0 + col4) = o;
        }
    }
}

// ---------------------------------------------------------------------------
// k_convx: x f32 [B,512,4096] -> Xh f16 (same layout) + XT f16 [B,4096,512]
//          + rowsums s[b][c] = sum_n x  (f32 atomics, s pre-zeroed by k_prep)
// ---------------------------------------------------------------------------
__global__ __launch_bounds__(256) void k_convx(const float* __restrict__ x,
                                               u16* __restrict__ Xh,
                                               u16* __restrict__ XT,
                                               float* __restrict__ s)
{
    __shared__ u16 tile[64][70];
    const int t  = threadIdx.x;
    const int b  = blockIdx.z;
    const int c0 = blockIdx.y * 64;
    const int n0 = blockIdx.x * 64;
    const int rr   = t >> 4;
    const int col4 = (t & 15) * 4;

    const float* src = x + ((size_t)b * 512 + c0) * 4096 + n0;
    u16* xh = Xh + ((size_t)b * 512 + c0) * 4096 + n0;
#pragma unroll
    for (int i = 0; i < 4; i++) {
        int row = i * 16 + rr;
        float4 v = *(const float4*)(src + (size_t)row * 4096 + col4);
        ushort4 h;
        h.x = f2h(v.x); h.y = f2h(v.y); h.z = f2h(v.z); h.w = f2h(v.w);
        *(ushort4*)&tile[row][col4] = h;
        *(ushort4*)(xh + (size_t)row * 4096 + col4) = h;
        float p = v.x + v.y + v.z + v.w;
        p += __shfl_xor(p, 1); p += __shfl_xor(p, 2);
        p += __shfl_xor(p, 4); p += __shfl_xor(p, 8);
        if ((t & 15) == 0) atomicAdd(&s[b * 512 + c0 + row], p);
    }
    __syncthreads();
    u16* dst = XT + ((size_t)b * 4096 + n0) * 512 + c0;
#pragma unroll
    for (int i = 0; i < 4; i++) {
        int nrow = i * 16 + rr;
        ushort4 o;
        o.x = tile[col4 + 0][nrow];
        o.y = tile[col4 + 1][nrow];
        o.z = tile[col4 + 2][nrow];
        o.w = tile[col4 + 3][nrow];
        *(ushort4*)(dst + (size_t)nrow * 512 + col4) = o;
    }
}

// ---------------------------------------------------------------------------
// k_gram: Gp[ks][b] = Xh[b, :, ks*2048:+2048] * (same)^T   split-K=2, f32 out
// grid (4,4,16): bz = b*2 + ks
// ---------------------------------------------------------------------------
__global__ __launch_bounds__(256) void k_gram(const u16* __restrict__ Xh,
                                              float* __restrict__ Gp)
{
    __shared__ u16 smem[2][8192];        // 32 KB (double-buffered)
    const int n0 = blockIdx.x * 128;
    const int m0 = blockIdx.y * 128;
    const int bz = blockIdx.z;
    const int b  = bz >> 1, ks = bz & 1;

    const u16* Ap = Xh + (size_t)b * 512 * 4096 + (size_t)m0 * 4096 + ks * 2048;
    const u16* Bp = Xh + (size_t)b * 512 * 4096 + (size_t)n0 * 4096 + ks * 2048;

    f32x4 acc[4][4];
    zero_acc(acc);
    gemm_nt_f16(&smem[0][0], Ap, 4096, Bp, 4096, 2048, acc);

    const int t = threadIdx.x, w = t >> 6, lane = t & 63;
    const int wm = (w >> 1) * 64, wn = (w & 1) * 64;
    const int cn = lane & 15, cq = lane >> 4;

    float* outp = Gp + ((size_t)(ks * 8 + b) * 512 + m0) * 512 + n0;
#pragma unroll
    for (int mi = 0; mi < 4; mi++)
#pragma unroll
        for (int ni = 0; ni < 4; ni++)
#pragma unroll
            for (int r = 0; r < 4; r++) {
                int m = wm + mi * 16 + cq * 4 + r;
                int n = wn + ni * 16 + cn;
                outp[(size_t)m * 512 + n] = acc[mi][ni][r];
            }
}

// ---------------------------------------------------------------------------
// k_gred: G = sum of 2 split-K partials; store hi/lo f16 pair
// Ghl[b][d][0:512] = hi(G[d][:]), [512:1024] = lo.
// blocks 0..127 additionally compute (after their gred work):
//   ubar[b][i] = (Wq s_b)[i] + 4096*bq[i];  vv[b][j] = (Wk s_b)[j]
// ---------------------------------------------------------------------------
__global__ __launch_bounds__(256) void k_gred(const float* __restrict__ Gp,
                                              u16* __restrict__ Ghl,
                                              const float* __restrict__ wq,
                                              const float* __restrict__ bq,
                                              const float* __restrict__ wk,
                                              const float* __restrict__ s,
                                              float* __restrict__ ubar,
                                              float* __restrict__ vv)
{
    const size_t idx = ((size_t)blockIdx.x * 256 + threadIdx.x) * 4;
    const size_t st = (size_t)8 * 512 * 512;
    float4 g0 = *(const float4*)(Gp + idx);
    float4 g1 = *(const float4*)(Gp + idx + st);
    float gx = g0.x + g1.x;
    float gy = g0.y + g1.y;
    float gz = g0.z + g1.z;
    float gw = g0.w + g1.w;
    ushort4 hi, lo;
    hi.x = f2h(gx); lo.x = f2h(gx - h2f(hi.x));
    hi.y = f2h(gy); lo.y = f2h(gy - h2f(hi.y));
    hi.z = f2h(gz); lo.z = f2h(gz - h2f(hi.z));
    hi.w = f2h(gw); lo.w = f2h(gw - h2f(hi.w));
    const size_t row = idx >> 9;                 // b*512 + d
    const int c = (int)(idx & 511);
    *(ushort4*)(Ghl + row * 1024 + c) = hi;
    *(ushort4*)(Ghl + row * 1024 + 512 + c) = lo;

    if (blockIdx.x < 128) {                      // fused k_uv
        const int b = blockIdx.x >> 4;
        const int sub = blockIdx.x & 15;
        const int which = sub >> 3;
        const int r0 = (sub & 7) * 64;
        const int t = threadIdx.x;
        const int i = r0 + (t >> 2), l4 = t & 3;
        const float* W = which ? wk : wq;
        const float* sb = s + b * 512;
        float acc = 0.f;
#pragma unroll 4
        for (int k = 0; k < 32; k++) {
            int c2 = k * 16 + l4 * 4;
            float4 w4 = *(const float4*)(W + (size_t)i * 512 + c2);
            float4 s4 = *(const float4*)(sb + c2);
            acc += w4.x * s4.x + w4.y * s4.y + w4.z * s4.z + w4.w * s4.w;
        }
        acc += __shfl_xor(acc, 1);
        acc += __shfl_xor(acc, 2);
        if (l4 == 0) {
            if (which) vv[b * 512 + i] = acc;
            else       ubar[b * 512 + i] = acc + 4096.0f * bq[i];
        }
    }
}

// ---------------------------------------------------------------------------
// k_T: T[b] = [Wq|Wq] * Ghl[b]^T  (K=1024 hi/lo => f32-precise Wq*G), f16 out
// grid (4,4,8)
// ---------------------------------------------------------------------------
__global__ __launch_bounds__(256) void k_T(const u16* __restrict__ Wq2,
                                           const u16* __restrict__ Ghl,
                                           u16* __restrict__ Tb)
{
    __shared__ u16 smem[2][8192];
    const int n0 = blockIdx.x * 128;
    const int m0 = blockIdx.y * 128;
    const int b  = blockIdx.z;

    const u16* Ap = Wq2 + (size_t)m0 * 1024;
    const u16* Bp = Ghl + (size_t)b * 512 * 1024 + (size_t)n0 * 1024;

    f32x4 acc[4][4];
    zero_acc(acc);
    gemm_nt_f16(&smem[0][0], Ap, 1024, Bp, 1024, 1024, acc);

    const int t = threadIdx.x, w = t >> 6, lane = t & 63;
    const int wm = (w >> 1) * 64, wn = (w & 1) * 64;
    const int cn = lane & 15, cq = lane >> 4;

    u16* outp = Tb + ((size_t)b * 512 + m0) * 512 + n0;
#pragma unroll
    for (int mi = 0; mi < 4; mi++)
#pragma unroll
        for (int ni = 0; ni < 4; ni++)
#pragma unroll
            for (int r = 0; r < 4; r++) {
                int m = wm + mi * 16 + cq * 4 + r;
                int n = wn + ni * 16 + cn;
                outp[(size_t)m * 512 + n] = f2h(acc[mi][ni][r]);
            }
}

// ---------------------------------------------------------------------------
// k_S: fused  S = T*Wk^T + ubar*bk^T + bq*vv^T  -> row softmax -> P (f16)
//      also pbv[b][i] = sum_j P[i][j]*bv[j]
// Block = 16 rows x full 512 cols (rows complete -> in-block softmax).
// 4 waves; wave w owns cols [w*128, w*128+128).  grid (32, 8).
// 2-phase double-buffered staging (As 16x32 + Bs 512x32 per buffer).
// ---------------------------------------------------------------------------
__global__ __launch_bounds__(256) void k_S(
    const u16* __restrict__ Tb, const u16* __restrict__ Wkh,
    const float* __restrict__ ubar, const float* __restrict__ vv,
    const float* __restrict__ bq, const float* __restrict__ bk,
    const float* __restrict__ bv,
    u16* __restrict__ P, float* __restrict__ pbv)
{
    __shared__ u16 smem[2][16896];       // As 16x32 (512) + Bs 512x32 (16384)
    __shared__ float redm[16][4];
    __shared__ float reds[16][4][2];

    const int m0 = blockIdx.x * 16;
    const int b  = blockIdx.y;
    const int t = threadIdx.x, w = t >> 6, lane = t & 63;
    const int srow = lane >> 2;
    const int schunk = ((lane & 3) ^ ((srow >> 1) & 3)) * 8;
    const u16* gA = Tb + ((size_t)b * 512 + m0 + srow) * 512 + schunk;
    const int fr = lane & 15, fq = lane >> 4;
    const int fc = (fq ^ ((fr >> 1) & 3)) * 8;

    f32x4 acc[8];
#pragma unroll
    for (int i = 0; i < 8; i++) { f32x4 z = {0.f,0.f,0.f,0.f}; acc[i] = z; }

#define STAGE_S(buf, k0)                                                     \
    {   u16* As = smem[buf]; u16* Bs = smem[buf] + 512;                      \
        if (w == 0) async_copy16(gA + (k0), As);                             \
        _Pragma("unroll")                                                    \
        for (int ii = 0; ii < 8; ii++) {                                     \
            int rbase = w * 128 + ii * 16;                                   \
            async_copy16(Wkh + (size_t)(rbase + srow) * 512 + (k0) + schunk, \
                         Bs + rbase * 32);  }  }

#define COMPUTE_S(buf)                                                       \
    {   const u16* As = smem[buf]; const u16* Bs = smem[buf] + 512;          \
        f16x8 af = *(const f16x8*)(As + fr * 32 + fc);                       \
        _Pragma("unroll")                                                    \
        for (int ni = 0; ni < 8; ni++) {                                     \
            f16x8 bf = *(const f16x8*)(Bs + (w * 128 + ni * 16 + fr) * 32 + fc); \
            acc[ni] = __builtin_amdgcn_mfma_f32_16x16x32_f16(af, bf, acc[ni], 0, 0, 0); \
        }  }

    STAGE_S(0, 0);
    __syncthreads();
    int cur = 0;
    for (int k0 = 32; k0 < 512; k0 += 32) {
        STAGE_S(cur ^ 1, k0);
        COMPUTE_S(cur);
        __syncthreads();
        cur ^= 1;
    }
    COMPUTE_S(cur);
#undef STAGE_S
#undef COMPUTE_S

    const int cn = lane & 15, cq = lane >> 4;
    float ub[4], bqr[4];
#pragma unroll
    for (int r = 0; r < 4; r++) {
        int i = m0 + cq * 4 + r;
        ub[r]  = ubar[b * 512 + i];
        bqr[r] = bq[i];
    }
    float vj[8], bkj[8], bvj[8];
#pragma unroll
    for (int ni = 0; ni < 8; ni++) {
        int j = w * 128 + ni * 16 + cn;
        vj[ni]  = vv[b * 512 + j];
        bkj[ni] = bk[j];
        bvj[ni] = bv[j];
    }
    float sv[8][4], mr[4];
#pragma unroll
    for (int r = 0; r < 4; r++) mr[r] = -1e30f;
#pragma unroll
    for (int ni = 0; ni < 8; ni++)
#pragma unroll
        for (int r = 0; r < 4; r++) {
            sv[ni][r] = acc[ni][r] + ub[r] * bkj[ni] + bqr[r] * vj[ni];
            mr[r] = fmaxf(mr[r], sv[ni][r]);
        }
#pragma unroll
    for (int r = 0; r < 4; r++)
        for (int o = 1; o < 16; o <<= 1) mr[r] = fmaxf(mr[r], __shfl_xor(mr[r], o));
    if (cn == 0) {
#pragma unroll
        for (int r = 0; r < 4; r++) redm[cq * 4 + r][w] = mr[r];
    }
    __syncthreads();
#pragma unroll
    for (int r = 0; r < 4; r++) {
        int row = cq * 4 + r;
        mr[r] = fmaxf(fmaxf(redm[row][0], redm[row][1]),
                      fmaxf(redm[row][2], redm[row][3]));
    }
    float e[8][4], se[4], sebv[4];
#pragma unroll
    for (int r = 0; r < 4; r++) { se[r] = 0.f; sebv[r] = 0.f; }
#pragma unroll
    for (int ni = 0; ni < 8; ni++)
#pragma unroll
        for (int r = 0; r < 4; r++) {
            float ev = __expf(sv[ni][r] - mr[r]);
            e[ni][r] = ev;
            se[r]   += ev;
            sebv[r] += ev * bvj[ni];
        }
#pragma unroll
    for (int r = 0; r < 4; r++)
        for (int o = 1; o < 16; o <<= 1) {
            se[r]   += __shfl_xor(se[r], o);
            sebv[r] += __shfl_xor(sebv[r], o);
        }
    if (cn == 0) {
#pragma unroll
        for (int r = 0; r < 4; r++) {
            reds[cq * 4 + r][w][0] = se[r];
            reds[cq * 4 + r][w][1] = sebv[r];
        }
    }
    __syncthreads();
#pragma unroll
    for (int r = 0; r < 4; r++) {
        int row = cq * 4 + r;
        float S  = reds[row][0][0] + reds[row][1][0] + reds[row][2][0] + reds[row][3][0];
        float SB = reds[row][0][1] + reds[row][1][1] + reds[row][2][1] + reds[row][3][1];
        float inv = 1.0f / S;
#pragma unroll
        for (int ni = 0; ni < 8; ni++)
            P[((size_t)b * 512 + m0 + row) * 512 + w * 128 + ni * 16 + cn] =
                f2h(e[ni][r] * inv);
        if (w == 0 && cn == 0) pbv[b * 512 + m0 + row] = SB * inv;
    }
}

// ---------------------------------------------------------------------------
// k_M: M2[b] = P[b] * Wv  (contraction over P cols / Wv rows => B = WvT), f16
// grid (4,4,8)
// ---------------------------------------------------------------------------
__global__ __launch_bounds__(256) void k_M(const u16* __restrict__ P,
                                           const u16* __restrict__ WvT,
                                           u16* __restrict__ M2)
{
    __shared__ u16 smem[2][8192];
    const int n0 = blockIdx.x * 128;
    const int m0 = blockIdx.y * 128;
    const int b  = blockIdx.z;

    const u16* Ap = P + (size_t)b * 512 * 512 + (size_t)m0 * 512;
    const u16* Bp = WvT + (size_t)n0 * 512;

    f32x4 acc[4][4];
    zero_acc(acc);
    gemm_nt_f16(&smem[0][0], Ap, 512, Bp, 512, 512, acc);

    const int t = threadIdx.x, w = t >> 6, lane = t & 63;
    const int wm = (w >> 1) * 64, wn = (w & 1) * 64;
    const int cn = lane & 15, cq = lane >> 4;

    u16* outp = M2 + ((size_t)b * 512 + m0) * 512 + n0;
#pragma unroll
    for (int mi = 0; mi < 4; mi++)
#pragma unroll
        for (int ni = 0; ni < 4; ni++)
#pragma unroll
            for (int r = 0; r < 4; r++) {
                int m = wm + mi * 16 + cq * 4 + r;
                int n = wn + ni * 16 + cn;
                outp[(size_t)m * 512 + n] = f2h(acc[mi][ni][r]);
            }
}

// ---------------------------------------------------------------------------
// k_out: out = M2 * X + pbv*1^T + x_res   (residual from Xh f16), f32 out
// grid (32, 4, 8)
// ---------------------------------------------------------------------------
__global__ __launch_bounds__(256) void k_out(const u16* __restrict__ M2,
                                             const u16* __restrict__ XT,
                                             const u16* __restrict__ Xh,
                                             const float* __restrict__ pbv,
                                             float* __restrict__ out)
{
    __shared__ u16 smem[2][8192];
    const int n0 = blockIdx.x * 128;
    const int m0 = blockIdx.y * 128;
    const int b  = blockIdx.z;

    const u16* Ap = M2 + (size_t)b * 512 * 512 + (size_t)m0 * 512;
    const u16* Bp = XT + (size_t)b * 4096 * 512 + (size_t)n0 * 512;

    f32x4 acc[4][4];
    zero_acc(acc);
    gemm_nt_f16(&smem[0][0], Ap, 512, Bp, 512, 512, acc);

    const int t = threadIdx.x, w = t >> 6, lane = t & 63;
    const int wm = (w >> 1) * 64, wn = (w & 1) * 64;
    const int cn = lane & 15, cq = lane >> 4;

#pragma unroll
    for (int mi = 0; mi < 4; mi++)
#pragma unroll
        for (int ni = 0; ni < 4; ni++)
#pragma unroll
            for (int r = 0; r < 4; r++) {
                int m = m0 + wm + mi * 16 + cq * 4 + r;
                int n = n0 + wn + ni * 16 + cn;
                size_t idx = ((size_t)b * 512 + m) * 4096 + n;
                out[idx] = acc[mi][ni][r] + pbv[b * 512 + m] + h2f(Xh[idx]);
            }
}

// ---------------------------------------------------------------------------
// ws layout (bytes), high-water ~120 MiB:
//   Wq2  [512][1024] f16   @ 0          (1048576)
//   Wkh  [512][512]  f16   @ 1048576    (524288)
//   WvT  [512][512]  f16   @ 1572864    (524288)
//   s    [8][512]    f32   @ 2097152    (16384)
//   ubar [8][512]    f32   @ 2113536    (16384)
//   vv   [8][512]    f32   @ 2129920    (16384)
//   pbv  [8][512]    f32   @ 2146304    (16384)
//   Xh   [8][512][4096] f16 @ 2162688   (33554432)
//   XT   [8][4096][512] f16 @ 35717120  (33554432)
//   Gp   [2][8][512][512] f32 @ 69271552 (16777216)
//   Ghl  [8][512][1024] f16 @ 86048768  (8388608)
//   Tb   [8][512][512] f16  @ 94437376  (4194304)
//   P    [8][512][512] f16  @ 98631680  (4194304)
//   M2   [8][512][512] f16  @ 102825984 (4194304)
// ---------------------------------------------------------------------------
extern "C" void kernel_launch(void* const* d_in, const int* in_sizes, int n_in,
                              void* d_out, int out_size, void* d_ws, size_t ws_size,
                              hipStream_t stream)
{
    const float* x  = (const float*)d_in[0];
    const float* wq = (const float*)d_in[1];
    const float* bq = (const float*)d_in[2];
    const float* wk = (const float*)d_in[3];
    const float* bk = (const float*)d_in[4];
    const float* wv = (const float*)d_in[5];
    const float* bv = (const float*)d_in[6];
    float* out = (float*)d_out;

    char* ws = (char*)d_ws;
    u16*   Wq2  = (u16*)(ws);
    u16*   Wkh  = (u16*)(ws + 1048576);
    u16*   WvT  = (u16*)(ws + 1572864);
    float* s    = (float*)(ws + 2097152);
    float* ubar = (float*)(ws + 2113536);
    float* vv   = (float*)(ws + 2129920);
    float* pbv  = (float*)(ws + 2146304);
    u16*   Xh   = (u16*)(ws + 2162688);
    u16*   XT   = (u16*)(ws + 35717120);
    float* Gp   = (float*)(ws + 69271552);
    u16*   Ghl  = (u16*)(ws + 86048768);
    u16*   Tb   = (u16*)(ws + 94437376);
    u16*   P    = (u16*)(ws + 98631680);
    u16*   M2   = (u16*)(ws + 102825984);

    k_prep<<<dim3(576), dim3(256), 0, stream>>>(wq, wk, wv, Wq2, Wkh, WvT, s);
    k_convx<<<dim3(64, 8, 8), dim3(256), 0, stream>>>(x, Xh, XT, s);
    k_gram<<<dim3(4, 4, 16), dim3(256), 0, stream>>>(Xh, Gp);
    k_gred<<<dim3(2048), dim3(256), 0, stream>>>(Gp, Ghl, wq, bq, wk, s, ubar, vv);
    k_T<<<dim3(4, 4, 8), dim3(256), 0, stream>>>(Wq2, Ghl, Tb);
    k_S<<<dim3(32, 8), dim3(256), 0, stream>>>(Tb, Wkh, ubar, vv, bq, bk, bv, P, pbv);
    k_M<<<dim3(4, 4, 8), dim3(256), 0, stream>>>(P, WvT, M2);
    k_out<<<dim3(32, 4, 8), dim3(256), 0, stream>>>(M2, XT, Xh, pbv, out);
}

// Round 3
// 255.294 us; speedup vs baseline: 1.0945x; 1.0945x over previous
//
#include <hip/hip_runtime.h>
#include <cstdint>

typedef unsigned short u16;
typedef unsigned int   u32;
typedef _Float16 f16;

typedef __attribute__((ext_vector_type(8))) _Float16 f16x8;   // 8 fp16 = 4 VGPRs
typedef __attribute__((ext_vector_type(4))) float    f32x4;   // MFMA accumulator

__device__ __forceinline__ u16 f2h(float f) {
    union { f16 h; u16 u; } c; c.h = (f16)f; return c.u;      // v_cvt_f16_f32 RTNE
}
__device__ __forceinline__ float h2f(u16 u) {
    union { u16 u; f16 h; } c; c.u = u; return (float)c.h;
}

// async global->LDS, 16B per lane; LDS dest = wave-uniform base + lane*16
__device__ __forceinline__ void async_copy16(const u16* g, u16* lds) {
    __builtin_amdgcn_global_load_lds(
        (const __attribute__((address_space(1))) void*)g,
        (__attribute__((address_space(3))) void*)lds,
        16, 0, 0);
}

// ---------------------------------------------------------------------------
// fp16 NT GEMM core, BK=64 as two 32-wide sub-tiles (identical proven layout):
//   C[128,128] += A[128,K] * B[128,K]^T, K contiguous both.
// 256 thr = 4 waves (2x2), each wave 64x64 = 4x4 MFMA 16x16x32.
// LDS 32 KB: As0@0, As1@4096, Bs0@8192, Bs1@12288 (u16 offsets), each
// [128][32] XOR-swizzled (0 bank conflicts, measured).  Sync structure is the
// round-1 proven form (stage -> sync -> compute -> sync) but HALF the
// iterations => half the vmcnt(0) barrier drains.
// ---------------------------------------------------------------------------
__device__ __forceinline__ void gemm_nt_f16(
    u16* smem, const u16* __restrict__ A, int lda,
    const u16* __restrict__ B, int ldb, int K, f32x4 acc[4][4])
{
    const int t = threadIdx.x, w = t >> 6, lane = t & 63;
    const int srow = lane >> 2;                    // 0..15 within chunk
    const int skc  = (((lane & 3) ^ ((lane >> 3) & 3)) * 8);  // swizzled
    const int ra0 = (w*2+0)*16 + srow, ra1 = (w*2+1)*16 + srow;
    const u16* gA0 = A + (size_t)ra0 * lda + skc;
    const u16* gA1 = A + (size_t)ra1 * lda + skc;
    const u16* gB0 = B + (size_t)ra0 * ldb + skc;
    const u16* gB1 = B + (size_t)ra1 * ldb + skc;
    u16* lA0 = smem + (w*2+0)*512;                 // row base within a 32-wide tile
    u16* lA1 = smem + (w*2+1)*512;
    const int fr = lane & 15, fq = lane >> 4;
    const int fc = (fq ^ ((fr >> 1) & 3)) * 8;     // swizzled fragment chunk
    const int wm = (w >> 1) * 64, wn = (w & 1) * 64;
    const int fAo = (wm + fr) * 32 + fc;
    const int fBo = (wn + fr) * 32 + fc;

    for (int k0 = 0; k0 < K; k0 += 64) {
        async_copy16(gA0 + k0,      lA0);
        async_copy16(gA1 + k0,      lA1);
        async_copy16(gA0 + k0 + 32, lA0 + 4096);
        async_copy16(gA1 + k0 + 32, lA1 + 4096);
        async_copy16(gB0 + k0,      lA0 + 8192);
        async_copy16(gB1 + k0,      lA1 + 8192);
        async_copy16(gB0 + k0 + 32, lA0 + 12288);
        async_copy16(gB1 + k0 + 32, lA1 + 12288);
        __syncthreads();
        {   // k-sub 0  (disjoint scope: fragment regs reused by sub 1)
            f16x8 af[4], bf[4];
#pragma unroll
            for (int i = 0; i < 4; i++) af[i] = *(const f16x8*)(smem + fAo + i * 512);
#pragma unroll
            for (int i = 0; i < 4; i++) bf[i] = *(const f16x8*)(smem + 8192 + fBo + i * 512);
#pragma unroll
            for (int mi = 0; mi < 4; mi++)
#pragma unroll
                for (int ni = 0; ni < 4; ni++)
                    acc[mi][ni] = __builtin_amdgcn_mfma_f32_16x16x32_f16(
                        af[mi], bf[ni], acc[mi][ni], 0, 0, 0);
        }
        {   // k-sub 1
            f16x8 af[4], bf[4];
#pragma unroll
            for (int i = 0; i < 4; i++) af[i] = *(const f16x8*)(smem + 4096 + fAo + i * 512);
#pragma unroll
            for (int i = 0; i < 4; i++) bf[i] = *(const f16x8*)(smem + 12288 + fBo + i * 512);
#pragma unroll
            for (int mi = 0; mi < 4; mi++)
#pragma unroll
                for (int ni = 0; ni < 4; ni++)
                    acc[mi][ni] = __builtin_amdgcn_mfma_f32_16x16x32_f16(
                        af[mi], bf[ni], acc[mi][ni], 0, 0, 0);
        }
        __syncthreads();
    }
}

__device__ __forceinline__ void zero_acc(f32x4 acc[4][4]) {
#pragma unroll
    for (int i = 0; i < 4; i++)
#pragma unroll
        for (int j = 0; j < 4; j++) {
            f32x4 z = {0.f, 0.f, 0.f, 0.f};
            acc[i][j] = z;
        }
}

// ---------------------------------------------------------------------------
// k_prep: blocks 0..511  : Wq -> duplicated f16 [512][1024] ([Wq|Wq]),
//                          Wk -> f16 [512][512]; zero rowsum accumulator s.
//         blocks 512..575: WvT[c][d] = f16(wv[d][c])
// ---------------------------------------------------------------------------
__global__ __launch_bounds__(256) void k_prep(const float* __restrict__ wq,
                                              const float* __restrict__ wk,
                                              const float* __restrict__ wv,
                                              u16* __restrict__ Wq2,
                                              u16* __restrict__ Wkh,
                                              u16* __restrict__ WvT,
                                              float* __restrict__ s)
{
    if (blockIdx.x < 512) {
        const int t = blockIdx.x * 256 + threadIdx.x;   // 0..131071
        if (t < 4096) s[t] = 0.f;
        const int e = t * 4;
        const int sel = e >> 18;                        // 0: wq, 1: wk
        const int off = e & 262143;
        const float* src = sel ? wk : wq;
        float4 v = *(const float4*)(src + off);
        ushort4 h;
        h.x = f2h(v.x); h.y = f2h(v.y); h.z = f2h(v.z); h.w = f2h(v.w);
        if (sel == 0) {
            int i = off >> 9, c = off & 511;
            *(ushort4*)(Wq2 + (size_t)i * 1024 + c) = h;
            *(ushort4*)(Wq2 + (size_t)i * 1024 + 512 + c) = h;
        } else {
            *(ushort4*)(Wkh + off) = h;
        }
    } else {
        __shared__ u16 tile[64][70];
        const int bx = blockIdx.x - 512;                // 0..63
        const int t = threadIdx.x;
        const int d0 = (bx >> 3) * 64;
        const int c0 = (bx & 7) * 64;
        const int rr = t >> 4, col4 = (t & 15) * 4;
#pragma unroll
        for (int i = 0; i < 4; i++) {
            int row = i * 16 + rr;                      // d offset
            float4 v = *(const float4*)(wv + (size_t)(d0 + row) * 512 + c0 + col4);
            ushort4 h;
            h.x = f2h(v.x); h.y = f2h(v.y); h.z = f2h(v.z); h.w = f2h(v.w);
            *(ushort4*)&tile[row][col4] = h;
        }
        __syncthreads();
#pragma unroll
        for (int i = 0; i < 4; i++) {
            int crow = i * 16 + rr;                     // c offset
            ushort4 o;
            o.x = tile[col4 + 0][crow];
            o.y = tile[col4 + 1][crow];
            o.z = tile[col4 + 2][crow];
            o.w = tile[col4 + 3][crow];
            *(ushort4*)(WvT + (size_t)(c0 + crow) * 512 + d0 + col4) = o;
        }
    }
}

// ---------------------------------------------------------------------------
// k_convx: x f32 [B,512,4096] -> Xh f16 (same layout) + XT f16 [B,4096,512]
//          + rowsums s[b][c] = sum_n x  (f32 atomics, s pre-zeroed by k_prep)
// ---------------------------------------------------------------------------
__global__ __launch_bounds__(256) void k_convx(const float* __restrict__ x,
                                               u16* __restrict__ Xh,
                                               u16* __restrict__ XT,
                                               float* __restrict__ s)
{
    __shared__ u16 tile[64][70];
    const int t  = threadIdx.x;
    const int b  = blockIdx.z;
    const int c0 = blockIdx.y * 64;
    const int n0 = blockIdx.x * 64;
    const int rr   = t >> 4;
    const int col4 = (t & 15) * 4;

    const float* src = x + ((size_t)b * 512 + c0) * 4096 + n0;
    u16* xh = Xh + ((size_t)b * 512 + c0) * 4096 + n0;
#pragma unroll
    for (int i = 0; i < 4; i++) {
        int row = i * 16 + rr;
        float4 v = *(const float4*)(src + (size_t)row * 4096 + col4);
        ushort4 h;
        h.x = f2h(v.x); h.y = f2h(v.y); h.z = f2h(v.z); h.w = f2h(v.w);
        *(ushort4*)&tile[row][col4] = h;
        *(ushort4*)(xh + (size_t)row * 4096 + col4) = h;
        float p = v.x + v.y + v.z + v.w;
        p += __shfl_xor(p, 1); p += __shfl_xor(p, 2);
        p += __shfl_xor(p, 4); p += __shfl_xor(p, 8);
        if ((t & 15) == 0) atomicAdd(&s[b * 512 + c0 + row], p);
    }
    __syncthreads();
    u16* dst = XT + ((size_t)b * 4096 + n0) * 512 + c0;
#pragma unroll
    for (int i = 0; i < 4; i++) {
        int nrow = i * 16 + rr;
        ushort4 o;
        o.x = tile[col4 + 0][nrow];
        o.y = tile[col4 + 1][nrow];
        o.z = tile[col4 + 2][nrow];
        o.w = tile[col4 + 3][nrow];
        *(ushort4*)(dst + (size_t)nrow * 512 + col4) = o;
    }
}

// ---------------------------------------------------------------------------
// k_gram: Gp[ks][b] = Xh[b, :, ks*1024:+1024] * (same)^T   split-K=4, f32 out
// grid (4,4,32): bz = b*4 + ks   (512 blocks = 2/CU)
// ---------------------------------------------------------------------------
__global__ __launch_bounds__(256, 4) void k_gram(const u16* __restrict__ Xh,
                                                 float* __restrict__ Gp)
{
    __shared__ u16 smem[16384];          // 32 KB
    const int n0 = blockIdx.x * 128;
    const int m0 = blockIdx.y * 128;
    const int bz = blockIdx.z;
    const int b  = bz >> 2, ks = bz & 3;

    const u16* Ap = Xh + (size_t)b * 512 * 4096 + (size_t)m0 * 4096 + ks * 1024;
    const u16* Bp = Xh + (size_t)b * 512 * 4096 + (size_t)n0 * 4096 + ks * 1024;

    f32x4 acc[4][4];
    zero_acc(acc);
    gemm_nt_f16(smem, Ap, 4096, Bp, 4096, 1024, acc);

    const int t = threadIdx.x, w = t >> 6, lane = t & 63;
    const int wm = (w >> 1) * 64, wn = (w & 1) * 64;
    const int cn = lane & 15, cq = lane >> 4;

    float* outp = Gp + ((size_t)(ks * 8 + b) * 512 + m0) * 512 + n0;
#pragma unroll
    for (int mi = 0; mi < 4; mi++)
#pragma unroll
        for (int ni = 0; ni < 4; ni++)
#pragma unroll
            for (int r = 0; r < 4; r++) {
                int m = wm + mi * 16 + cq * 4 + r;
                int n = wn + ni * 16 + cn;
                outp[(size_t)m * 512 + n] = acc[mi][ni][r];
            }
}

// ---------------------------------------------------------------------------
// k_gred: G = sum of 4 split-K partials; store hi/lo f16 pair
// Ghl[b][d][0:512] = hi(G[d][:]), [512:1024] = lo.
// blocks 0..127 additionally compute (fused k_uv):
//   ubar[b][i] = (Wq s_b)[i] + 4096*bq[i];  vv[b][j] = (Wk s_b)[j]
// ---------------------------------------------------------------------------
__global__ __launch_bounds__(256) void k_gred(const float* __restrict__ Gp,
                                              u16* __restrict__ Ghl,
                                              const float* __restrict__ wq,
                                              const float* __restrict__ bq,
                                              const float* __restrict__ wk,
                                              const float* __restrict__ s,
                                              float* __restrict__ ubar,
                                              float* __restrict__ vv)
{
    const size_t idx = ((size_t)blockIdx.x * 256 + threadIdx.x) * 4;
    const size_t st = (size_t)8 * 512 * 512;
    float4 g0 = *(const float4*)(Gp + idx);
    float4 g1 = *(const float4*)(Gp + idx + st);
    float4 g2 = *(const float4*)(Gp + idx + 2 * st);
    float4 g3 = *(const float4*)(Gp + idx + 3 * st);
    float gx = g0.x + g1.x + g2.x + g3.x;
    float gy = g0.y + g1.y + g2.y + g3.y;
    float gz = g0.z + g1.z + g2.z + g3.z;
    float gw = g0.w + g1.w + g2.w + g3.w;
    ushort4 hi, lo;
    hi.x = f2h(gx); lo.x = f2h(gx - h2f(hi.x));
    hi.y = f2h(gy); lo.y = f2h(gy - h2f(hi.y));
    hi.z = f2h(gz); lo.z = f2h(gz - h2f(hi.z));
    hi.w = f2h(gw); lo.w = f2h(gw - h2f(hi.w));
    const size_t row = idx >> 9;                 // b*512 + d
    const int c = (int)(idx & 511);
    *(ushort4*)(Ghl + row * 1024 + c) = hi;
    *(ushort4*)(Ghl + row * 1024 + 512 + c) = lo;

    if (blockIdx.x < 128) {                      // fused k_uv
        const int b = blockIdx.x >> 4;
        const int sub = blockIdx.x & 15;
        const int which = sub >> 3;
        const int r0 = (sub & 7) * 64;
        const int t = threadIdx.x;
        const int i = r0 + (t >> 2), l4 = t & 3;
        const float* W = which ? wk : wq;
        const float* sb = s + b * 512;
        float acc = 0.f;
#pragma unroll 4
        for (int k = 0; k < 32; k++) {
            int c2 = k * 16 + l4 * 4;
            float4 w4 = *(const float4*)(W + (size_t)i * 512 + c2);
            float4 s4 = *(const float4*)(sb + c2);
            acc += w4.x * s4.x + w4.y * s4.y + w4.z * s4.z + w4.w * s4.w;
        }
        acc += __shfl_xor(acc, 1);
        acc += __shfl_xor(acc, 2);
        if (l4 == 0) {
            if (which) vv[b * 512 + i] = acc;
            else       ubar[b * 512 + i] = acc + 4096.0f * bq[i];
        }
    }
}

// ---------------------------------------------------------------------------
// k_T: T[b] = [Wq|Wq] * Ghl[b]^T  (K=1024 hi/lo => f32-precise Wq*G), f16 out
// grid (4,4,8)
// ---------------------------------------------------------------------------
__global__ __launch_bounds__(256, 4) void k_T(const u16* __restrict__ Wq2,
                                              const u16* __restrict__ Ghl,
                                              u16* __restrict__ Tb)
{
    __shared__ u16 smem[16384];
    const int n0 = blockIdx.x * 128;
    const int m0 = blockIdx.y * 128;
    const int b  = blockIdx.z;

    const u16* Ap = Wq2 + (size_t)m0 * 1024;
    const u16* Bp = Ghl + (size_t)b * 512 * 1024 + (size_t)n0 * 1024;

    f32x4 acc[4][4];
    zero_acc(acc);
    gemm_nt_f16(smem, Ap, 1024, Bp, 1024, 1024, acc);

    const int t = threadIdx.x, w = t >> 6, lane = t & 63;
    const int wm = (w >> 1) * 64, wn = (w & 1) * 64;
    const int cn = lane & 15, cq = lane >> 4;

    u16* outp = Tb + ((size_t)b * 512 + m0) * 512 + n0;
#pragma unroll
    for (int mi = 0; mi < 4; mi++)
#pragma unroll
        for (int ni = 0; ni < 4; ni++)
#pragma unroll
            for (int r = 0; r < 4; r++) {
                int m = wm + mi * 16 + cq * 4 + r;
                int n = wn + ni * 16 + cn;
                outp[(size_t)m * 512 + n] = f2h(acc[mi][ni][r]);
            }
}

// ---------------------------------------------------------------------------
// k_S: fused  S = T*Wk^T + ubar*bk^T + bq*vv^T  -> row softmax -> P (f16)
//      also pbv[b][i] = sum_j P[i][j]*bv[j]
// Block = 16 rows x full 512 cols (rows complete -> in-block softmax).
// 4 waves; wave w owns cols [w*128, w*128+128).  grid (32, 8).
// ---------------------------------------------------------------------------
__global__ __launch_bounds__(256) void k_S(
    const u16* __restrict__ Tb, const u16* __restrict__ Wkh,
    const float* __restrict__ ubar, const float* __restrict__ vv,
    const float* __restrict__ bq, const float* __restrict__ bk,
    const float* __restrict__ bv,
    u16* __restrict__ P, float* __restrict__ pbv)
{
    __shared__ u16 smem[16896];          // As 16x32 (512) + Bs 512x32 (16384)
    __shared__ float redm[16][4];
    __shared__ float reds[16][4][2];
    u16* As = smem; u16* Bs = smem + 512;

    const int m0 = blockIdx.x * 16;
    const int b  = blockIdx.y;
    const int t = threadIdx.x, w = t >> 6, lane = t & 63;
    const int srow = lane >> 2;
    const int schunk = ((lane & 3) ^ ((srow >> 1) & 3)) * 8;
    const u16* gA = Tb + ((size_t)b * 512 + m0 + srow) * 512 + schunk;
    const int fr = lane & 15, fq = lane >> 4;
    const int fc = (fq ^ ((fr >> 1) & 3)) * 8;

    f32x4 acc[8];
#pragma unroll
    for (int i = 0; i < 8; i++) { f32x4 z = {0.f,0.f,0.f,0.f}; acc[i] = z; }

    for (int k0 = 0; k0 < 512; k0 += 32) {
        if (w == 0) async_copy16(gA + k0, As);
#pragma unroll
        for (int ii = 0; ii < 8; ii++) {
            int rbase = w * 128 + ii * 16;
            async_copy16(Wkh + (size_t)(rbase + srow) * 512 + k0 + schunk,
                         Bs + rbase * 32);
        }
        __syncthreads();
        f16x8 af = *(const f16x8*)(As + fr * 32 + fc);
#pragma unroll
        for (int ni = 0; ni < 8; ni++) {
            f16x8 bf = *(const f16x8*)(Bs + (w * 128 + ni * 16 + fr) * 32 + fc);
            acc[ni] = __builtin_amdgcn_mfma_f32_16x16x32_f16(af, bf, acc[ni], 0, 0, 0);
        }
        __syncthreads();
    }

    const int cn = lane & 15, cq = lane >> 4;
    float ub[4], bqr[4];
#pragma unroll
    for (int r = 0; r < 4; r++) {
        int i = m0 + cq * 4 + r;
        ub[r]  = ubar[b * 512 + i];
        bqr[r] = bq[i];
    }
    float vj[8], bkj[8], bvj[8];
#pragma unroll
    for (int ni = 0; ni < 8; ni++) {
        int j = w * 128 + ni * 16 + cn;
        vj[ni]  = vv[b * 512 + j];
        bkj[ni] = bk[j];
        bvj[ni] = bv[j];
    }
    float sv[8][4], mr[4];
#pragma unroll
    for (int r = 0; r < 4; r++) mr[r] = -1e30f;
#pragma unroll
    for (int ni = 0; ni < 8; ni++)
#pragma unroll
        for (int r = 0; r < 4; r++) {
            sv[ni][r] = acc[ni][r] + ub[r] * bkj[ni] + bqr[r] * vj[ni];
            mr[r] = fmaxf(mr[r], sv[ni][r]);
        }
#pragma unroll
    for (int r = 0; r < 4; r++)
        for (int o = 1; o < 16; o <<= 1) mr[r] = fmaxf(mr[r], __shfl_xor(mr[r], o));
    if (cn == 0) {
#pragma unroll
        for (int r = 0; r < 4; r++) redm[cq * 4 + r][w] = mr[r];
    }
    __syncthreads();
#pragma unroll
    for (int r = 0; r < 4; r++) {
        int row = cq * 4 + r;
        mr[r] = fmaxf(fmaxf(redm[row][0], redm[row][1]),
                      fmaxf(redm[row][2], redm[row][3]));
    }
    float e[8][4], se[4], sebv[4];
#pragma unroll
    for (int r = 0; r < 4; r++) { se[r] = 0.f; sebv[r] = 0.f; }
#pragma unroll
    for (int ni = 0; ni < 8; ni++)
#pragma unroll
        for (int r = 0; r < 4; r++) {
            float ev = __expf(sv[ni][r] - mr[r]);
            e[ni][r] = ev;
            se[r]   += ev;
            sebv[r] += ev * bvj[ni];
        }
#pragma unroll
    for (int r = 0; r < 4; r++)
        for (int o = 1; o < 16; o <<= 1) {
            se[r]   += __shfl_xor(se[r], o);
            sebv[r] += __shfl_xor(sebv[r], o);
        }
    if (cn == 0) {
#pragma unroll
        for (int r = 0; r < 4; r++) {
            reds[cq * 4 + r][w][0] = se[r];
            reds[cq * 4 + r][w][1] = sebv[r];
        }
    }
    __syncthreads();
#pragma unroll
    for (int r = 0; r < 4; r++) {
        int row = cq * 4 + r;
        float S  = reds[row][0][0] + reds[row][1][0] + reds[row][2][0] + reds[row][3][0];
        float SB = reds[row][0][1] + reds[row][1][1] + reds[row][2][1] + reds[row][3][1];
        float inv = 1.0f / S;
#pragma unroll
        for (int ni = 0; ni < 8; ni++)
            P[((size_t)b * 512 + m0 + row) * 512 + w * 128 + ni * 16 + cn] =
                f2h(e[ni][r] * inv);
        if (w == 0 && cn == 0) pbv[b * 512 + m0 + row] = SB * inv;
    }
}

// ---------------------------------------------------------------------------
// k_M: M2[b] = P[b] * Wv  (contraction over P cols / Wv rows => B = WvT), f16
// grid (4,4,8)
// ---------------------------------------------------------------------------
__global__ __launch_bounds__(256, 4) void k_M(const u16* __restrict__ P,
                                              const u16* __restrict__ WvT,
                                              u16* __restrict__ M2)
{
    __shared__ u16 smem[16384];
    const int n0 = blockIdx.x * 128;
    const int m0 = blockIdx.y * 128;
    const int b  = blockIdx.z;

    const u16* Ap = P + (size_t)b * 512 * 512 + (size_t)m0 * 512;
    const u16* Bp = WvT + (size_t)n0 * 512;

    f32x4 acc[4][4];
    zero_acc(acc);
    gemm_nt_f16(smem, Ap, 512, Bp, 512, 512, acc);

    const int t = threadIdx.x, w = t >> 6, lane = t & 63;
    const int wm = (w >> 1) * 64, wn = (w & 1) * 64;
    const int cn = lane & 15, cq = lane >> 4;

    u16* outp = M2 + ((size_t)b * 512 + m0) * 512 + n0;
#pragma unroll
    for (int mi = 0; mi < 4; mi++)
#pragma unroll
        for (int ni = 0; ni < 4; ni++)
#pragma unroll
            for (int r = 0; r < 4; r++) {
                int m = wm + mi * 16 + cq * 4 + r;
                int n = wn + ni * 16 + cn;
                outp[(size_t)m * 512 + n] = f2h(acc[mi][ni][r]);
            }
}

// ---------------------------------------------------------------------------
// k_out: out = M2 * X + pbv*1^T + x_res   (residual from Xh f16), f32 out
// grid (32, 4, 8)
// ---------------------------------------------------------------------------
__global__ __launch_bounds__(256, 4) void k_out(const u16* __restrict__ M2,
                                                const u16* __restrict__ XT,
                                                const u16* __restrict__ Xh,
                                                const float* __restrict__ pbv,
                                                float* __restrict__ out)
{
    __shared__ u16 smem[16384];
    const int n0 = blockIdx.x * 128;
    const int m0 = blockIdx.y * 128;
    const int b  = blockIdx.z;

    const u16* Ap = M2 + (size_t)b * 512 * 512 + (size_t)m0 * 512;
    const u16* Bp = XT + (size_t)b * 4096 * 512 + (size_t)n0 * 512;

    f32x4 acc[4][4];
    zero_acc(acc);
    gemm_nt_f16(smem, Ap, 512, Bp, 512, 512, acc);

    const int t = threadIdx.x, w = t >> 6, lane = t & 63;
    const int wm = (w >> 1) * 64, wn = (w & 1) * 64;
    const int cn = lane & 15, cq = lane >> 4;

#pragma unroll
    for (int mi = 0; mi < 4; mi++)
#pragma unroll
        for (int ni = 0; ni < 4; ni++)
#pragma unroll
            for (int r = 0; r < 4; r++) {
                int m = m0 + wm + mi * 16 + cq * 4 + r;
                int n = n0 + wn + ni * 16 + cn;
                size_t idx = ((size_t)b * 512 + m) * 4096 + n;
                out[idx] = acc[mi][ni][r] + pbv[b * 512 + m] + h2f(Xh[idx]);
            }
}

// ---------------------------------------------------------------------------
// ws layout (bytes), high-water ~118 MiB:
//   Wq2  [512][1024] f16   @ 0          (1048576)
//   Wkh  [512][512]  f16   @ 1048576    (524288)
//   WvT  [512][512]  f16   @ 1572864    (524288)
//   s    [8][512]    f32   @ 2097152    (16384)
//   ubar [8][512]    f32   @ 2113536    (16384)
//   vv   [8][512]    f32   @ 2129920    (16384)
//   pbv  [8][512]    f32   @ 2146304    (16384)
//   Xh   [8][512][4096] f16 @ 2162688   (33554432)
//   XT   [8][4096][512] f16 @ 35717120  (33554432)
//   Gp   [4][8][512][512] f32 @ 69271552 (33554432)
//   Ghl  [8][512][1024] f16 @ 102825984 (8388608)
//   Tb   [8][512][512] f16  @ 111214592 (4194304)
//   P    [8][512][512] f16  @ 115408896 (4194304)
//   M2   [8][512][512] f16  @ 119603200 (4194304)
// ---------------------------------------------------------------------------
extern "C" void kernel_launch(void* const* d_in, const int* in_sizes, int n_in,
                              void* d_out, int out_size, void* d_ws, size_t ws_size,
                              hipStream_t stream)
{
    const float* x  = (const float*)d_in[0];
    const float* wq = (const float*)d_in[1];
    const float* bq = (const float*)d_in[2];
    const float* wk = (const float*)d_in[3];
    const float* bk = (const float*)d_in[4];
    const float* wv = (const float*)d_in[5];
    const float* bv = (const float*)d_in[6];
    float* out = (float*)d_out;

    char* ws = (char*)d_ws;
    u16*   Wq2  = (u16*)(ws);
    u16*   Wkh  = (u16*)(ws + 1048576);
    u16*   WvT  = (u16*)(ws + 1572864);
    float* s    = (float*)(ws + 2097152);
    float* ubar = (float*)(ws + 2113536);
    float* vv   = (float*)(ws + 2129920);
    float* pbv  = (float*)(ws + 2146304);
    u16*   Xh   = (u16*)(ws + 2162688);
    u16*   XT   = (u16*)(ws + 35717120);
    float* Gp   = (float*)(ws + 69271552);
    u16*   Ghl  = (u16*)(ws + 102825984);
    u16*   Tb   = (u16*)(ws + 111214592);
    u16*   P    = (u16*)(ws + 115408896);
    u16*   M2   = (u16*)(ws + 119603200);

    k_prep<<<dim3(576), dim3(256), 0, stream>>>(wq, wk, wv, Wq2, Wkh, WvT, s);
    k_convx<<<dim3(64, 8, 8), dim3(256), 0, stream>>>(x, Xh, XT, s);
    k_gram<<<dim3(4, 4, 32), dim3(256), 0, stream>>>(Xh, Gp);
    k_gred<<<dim3(2048), dim3(256), 0, stream>>>(Gp, Ghl, wq, bq, wk, s, ubar, vv);
    k_T<<<dim3(4, 4, 8), dim3(256), 0, stream>>>(Wq2, Ghl, Tb);
    k_S<<<dim3(32, 8), dim3(256), 0, stream>>>(Tb, Wkh, ubar, vv, bq, bk, bv, P, pbv);
    k_M<<<dim3(4, 4, 8), dim3(256), 0, stream>>>(P, WvT, M2);
    k_out<<<dim3(32, 4, 8), dim3(256), 0, stream>>>(M2, XT, Xh, pbv, out);
}